// Round 7
// baseline (299.345 us; speedup 1.0000x reference)
//
#include <hip/hip_runtime.h>
#include <cstdint>
#include <cstddef>

typedef __attribute__((ext_vector_type(8))) _Float16 f16x8;
typedef __attribute__((ext_vector_type(4))) _Float16 f16x4;
typedef __attribute__((ext_vector_type(4))) float f32x4;

#define MFMA_16x16x32(a, b, c) __builtin_amdgcn_mfma_f32_16x16x32_f16((a), (b), (c), 0, 0, 0)

static constexpr int kB = 2, kS = 2048, kDim = 1024, kH = 16, kD = 64;
static constexpr int kM = kB * kS;  // 4096 rows total
// 1/sqrt(64) * log2(e), folded into Q at projection time
static constexpr float kQScale = 0.125f * 1.44269504088896340736f;

// ---------------- elementwise f32 -> f16 ----------------
__global__ void cvt_f32_to_f16(const float* __restrict__ in, _Float16* __restrict__ out, int n8) {
  int i = blockIdx.x * blockDim.x + threadIdx.x;
  if (i >= n8) return;
  const float4* p = (const float4*)in + (size_t)i * 2;
  float4 a = p[0], b = p[1];
  f16x8 h;
  h[0] = (_Float16)a.x; h[1] = (_Float16)a.y; h[2] = (_Float16)a.z; h[3] = (_Float16)a.w;
  h[4] = (_Float16)b.x; h[5] = (_Float16)b.y; h[6] = (_Float16)b.z; h[7] = (_Float16)b.w;
  ((f16x8*)out)[i] = h;
}

// ------------- W [K][N] f32  ->  Wt [N][K] f16 (4 matrices) -------------
__global__ void transpose_cvt_w(const float* __restrict__ w0, const float* __restrict__ w1,
                                const float* __restrict__ w2, const float* __restrict__ w3,
                                _Float16* __restrict__ o0, _Float16* __restrict__ o1,
                                _Float16* __restrict__ o2, _Float16* __restrict__ o3) {
  const float* w; _Float16* o;
  switch (blockIdx.z) {
    case 0: w = w0; o = o0; break;
    case 1: w = w1; o = o1; break;
    case 2: w = w2; o = o2; break;
    default: w = w3; o = o3; break;
  }
  __shared__ alignas(16) _Float16 tile[64][72];
  const int kt = blockIdx.x * 64;
  const int nt = blockIdx.y * 64;
  const int tr = threadIdx.x >> 4;
  const int tc = threadIdx.x & 15;
#pragma unroll
  for (int rr = 0; rr < 4; ++rr) {
    int r = rr * 16 + tr;
    float4 v = *(const float4*)&w[(size_t)(kt + r) * kDim + nt + tc * 4];
    f16x4 hv;
    hv[0] = (_Float16)v.x; hv[1] = (_Float16)v.y; hv[2] = (_Float16)v.z; hv[3] = (_Float16)v.w;
    *(f16x4*)&tile[r][tc * 4] = hv;
  }
  __syncthreads();
#pragma unroll
  for (int rr = 0; rr < 4; ++rr) {
    int nl = rr * 16 + tr;
    f16x4 hv;
    hv[0] = tile[tc * 4 + 0][nl];
    hv[1] = tile[tc * 4 + 1][nl];
    hv[2] = tile[tc * 4 + 2][nl];
    hv[3] = tile[tc * 4 + 3][nl];
    *(f16x4*)&o[(size_t)(nt + nl) * kDim + kt + tc * 4] = hv;
  }
}

// ------------- additive mask penalty, pre-scaled to log2 domain -------------
__global__ void mask_penalty(const float* __restrict__ mask, float* __restrict__ pen, int n) {
  int i = blockIdx.x * blockDim.x + threadIdx.x;
  if (i < n) pen[i] = -1.0e6f * (1.0f - mask[i]) * 1.44269504088896340736f;
}

// ------------- QKV projection GEMM (BK=64, R4 structure) -------------
__global__ __launch_bounds__(256, 2) void gemm_qkv(
    const _Float16* __restrict__ A,
    const _Float16* __restrict__ wt0, const _Float16* __restrict__ wt1, const _Float16* __restrict__ wt2,
    const float* __restrict__ bias0, const float* __restrict__ bias1, const float* __restrict__ bias2,
    _Float16* __restrict__ oq, _Float16* __restrict__ ok, _Float16* __restrict__ ov) {
  const _Float16* Bt; const float* bias; _Float16* out;
  switch (blockIdx.z) {
    case 0: Bt = wt0; bias = bias0; out = oq; break;
    case 1: Bt = wt1; bias = bias1; out = ok; break;
    default: Bt = wt2; bias = bias2; out = ov; break;
  }
  __shared__ alignas(16) _Float16 As[128 * 72];
  __shared__ alignas(16) _Float16 Bs[128 * 72];
  const int tid = threadIdx.x;
  const int lane = tid & 63;
  const int wave = tid >> 6;
  const int wm = wave & 1, wn = wave >> 1;
  const int l15 = lane & 15, quad = lane >> 4;
  const int m0 = blockIdx.x * 128, n0 = blockIdx.y * 128;

  f32x4 acc[4][4] = {};

  for (int k0 = 0; k0 < kDim; k0 += 64) {
    __syncthreads();
#pragma unroll
    for (int i = 0; i < 4; ++i) {
      int c = tid + 256 * i;
      int row = c >> 3, kc = (c & 7) * 8;
      *(f16x8*)&As[row * 72 + kc] = *(const f16x8*)&A[(size_t)(m0 + row) * kDim + k0 + kc];
      *(f16x8*)&Bs[row * 72 + kc] = *(const f16x8*)&Bt[(size_t)(n0 + row) * kDim + k0 + kc];
    }
    __syncthreads();
#pragma unroll
    for (int kk = 0; kk < 2; ++kk) {
      f16x8 af[4], bf[4];
#pragma unroll
      for (int t = 0; t < 4; ++t) af[t] = *(const f16x8*)&As[(wm * 64 + t * 16 + l15) * 72 + kk * 32 + quad * 8];
#pragma unroll
      for (int t = 0; t < 4; ++t) bf[t] = *(const f16x8*)&Bs[(wn * 64 + t * 16 + l15) * 72 + kk * 32 + quad * 8];
#pragma unroll
      for (int i = 0; i < 4; ++i)
#pragma unroll
        for (int j = 0; j < 4; ++j)
          acc[i][j] = MFMA_16x16x32(af[i], bf[j], acc[i][j]);
    }
  }

  const int mbase = m0 + wm * 64 + quad * 4;
  const int nbase = n0 + wn * 64 + l15;
  if (blockIdx.z == 2) {
#pragma unroll
    for (int j = 0; j < 4; ++j) {
      int n = nbase + j * 16;
      float bv = bias[n];
      int h = n >> 6, d = n & 63;
#pragma unroll
      for (int i = 0; i < 4; ++i) {
        int m = mbase + i * 16;
        int b = m >> 11, s = m & (kS - 1);
        f16x4 hv;
#pragma unroll
        for (int r = 0; r < 4; ++r) hv[r] = (_Float16)(acc[i][j][r] + bv);
        *(f16x4*)&out[((size_t)((b * kH + h) * kD + d)) * kS + s] = hv;
      }
    }
  } else {
    const float osc = (blockIdx.z == 0) ? kQScale : 1.0f;
#pragma unroll
    for (int j = 0; j < 4; ++j) {
      int n = nbase + j * 16;
      float bv = bias[n];
      int h = n >> 6, d = n & 63;
#pragma unroll
      for (int i = 0; i < 4; ++i) {
        int mrow = mbase + i * 16;
#pragma unroll
        for (int r = 0; r < 4; ++r) {
          int m = mrow + r;
          int b = m >> 11, s = m & (kS - 1);
          out[(size_t)(((b * kH + h) * kS) + s) * kD + d] = (_Float16)((acc[i][j][r] + bv) * osc);
        }
      }
    }
  }
}

// ------------- flash attention v3: barrier-free, 32q/wave (2 waves/SIMD) -------------
// S^T = K·Q^T, O^T = V^T·P^T. K [key][d] / V [d][s] rows are natively the
// A-fragment layout, so kf/vf load straight from global (L2-resident).
// 2048 waves total = 8 waves/CU = 2/SIMD -> cross-wave MFMA/VALU/VMEM overlap.
// No __syncthreads; only the per-wave P^T strip goes through LDS.
__global__ __launch_bounds__(256, 2) void attn(
    const _Float16* __restrict__ Q, const _Float16* __restrict__ K,
    const _Float16* __restrict__ V, const float* __restrict__ pen2,
    _Float16* __restrict__ ctx) {
  const int bh = blockIdx.y;
  const int b = bh >> 4;
  const int h = bh & 15;
  const int tid = threadIdx.x, lane = tid & 63, wave = tid >> 6;
  const int l15 = lane & 15, quad = lane >> 4;
  const int q0w = blockIdx.x * 128 + wave * 32;   // this wave's 32-q strip

  __shared__ alignas(16) _Float16 Pt[4][32 * 136];  // per-wave P^T strip [32q][128key]

  const _Float16* Qh = Q + (size_t)bh * kS * kD;
  const _Float16* Kh = K + (size_t)bh * kS * kD;   // [key][d]
  const _Float16* Vh = V + (size_t)bh * kS * kD;   // [d][s]

  // Q B-frags, loaded once: B[k=d=quad*8+j][n=q=l15]
  f16x8 qf[2][2];
#pragma unroll
  for (int t = 0; t < 2; ++t) {
    int qrow = q0w + t * 16 + l15;
#pragma unroll
    for (int kk = 0; kk < 2; ++kk)
      qf[t][kk] = *(const f16x8*)&Qh[(size_t)qrow * kD + kk * 32 + quad * 8];
  }

  // per-lane base pointers
  const _Float16* kbase = Kh + l15 * kD + quad * 8;
  const _Float16* vbase = Vh + (size_t)l15 * kS + quad * 8;
  const float* pbase = pen2 + b * kS + quad * 4;
  _Float16* ptw = &Pt[wave][0];

  f32x4 o_acc[2][4] = {};   // O^T: [q-tile][d-tile], C-layout (row=d, col=q)
  float l_part[2] = {};

  for (int kb = 0; kb < kS; kb += 128) {
    // V tile hoisted (reused by both q-tiles); kf/pn streamed
    f16x8 vf[4][4];
#pragma unroll
    for (int c = 0; c < 4; ++c)
#pragma unroll
      for (int ks = 0; ks < 4; ++ks)
        vf[ks][c] = *(const f16x8*)&vbase[(size_t)c * 16 * kS + kb + ks * 32];

    // S^T = K Q^T for both q-tiles (kf shared)
    f32x4 s[2][8] = {};
#pragma unroll
    for (int colt = 0; colt < 8; ++colt) {
      f16x8 kf0 = *(const f16x8*)&kbase[(size_t)(kb + colt * 16) * kD];
      f16x8 kf1 = *(const f16x8*)&kbase[(size_t)(kb + colt * 16) * kD + 32];
      s[0][colt] = MFMA_16x16x32(kf0, qf[0][0], s[0][colt]);
      s[1][colt] = MFMA_16x16x32(kf0, qf[1][0], s[1][colt]);
      s[0][colt] = MFMA_16x16x32(kf1, qf[0][1], s[0][colt]);
      s[1][colt] = MFMA_16x16x32(kf1, qf[1][1], s[1][colt]);
    }

    // P = exp2(S^T + pen[key]); key = colt*16+quad*4+r in regs -> b64 packs
#pragma unroll
    for (int colt = 0; colt < 8; ++colt) {
      f32x4 pn = *(const f32x4*)&pbase[kb + colt * 16];
#pragma unroll
      for (int t = 0; t < 2; ++t) {
        f16x4 ph;
        float lp = 0.0f;
#pragma unroll
        for (int r = 0; r < 4; ++r) {
          float pv = __builtin_exp2f(s[t][colt][r] + pn[r]);
          lp += pv;
          ph[r] = (_Float16)pv;
        }
        l_part[t] += lp;
        *(f16x4*)&ptw[(t * 16 + l15) * 136 + colt * 16 + quad * 4] = ph;
      }
    }

    // O^T += V^T P^T (vf shared across both q-tiles)
#pragma unroll
    for (int ks = 0; ks < 4; ++ks) {
      f16x8 pf0 = *(const f16x8*)&ptw[l15 * 136 + ks * 32 + quad * 8];
      f16x8 pf1 = *(const f16x8*)&ptw[(16 + l15) * 136 + ks * 32 + quad * 8];
#pragma unroll
      for (int c = 0; c < 4; ++c) {
        o_acc[0][c] = MFMA_16x16x32(vf[ks][c], pf0, o_acc[0][c]);
        o_acc[1][c] = MFMA_16x16x32(vf[ks][c], pf1, o_acc[1][c]);
      }
    }
  }

  // epilogue: reduce l over quads, normalize, b64 store
#pragma unroll
  for (int t = 0; t < 2; ++t) {
    float lsum = l_part[t];
    lsum += __shfl_xor(lsum, 16, 64);
    lsum += __shfl_xor(lsum, 32, 64);
    float inv = 1.0f / lsum;
    int q = q0w + t * 16 + l15;
#pragma unroll
    for (int c = 0; c < 4; ++c) {
      f16x4 oh;
#pragma unroll
      for (int r = 0; r < 4; ++r) oh[r] = (_Float16)(o_acc[t][c][r] * inv);
      *(f16x4*)&ctx[((size_t)(b * kS + q)) * kDim + h * kD + c * 16 + quad * 4] = oh;
    }
  }
}

// ------------- output GEMM (BK=64, R4 structure) -------------
__global__ __launch_bounds__(256, 2) void gemm_out(
    const _Float16* __restrict__ A, const _Float16* __restrict__ Bt,
    const float* __restrict__ bias, float* __restrict__ out) {
  __shared__ alignas(16) _Float16 As[128 * 72];
  __shared__ alignas(16) _Float16 Bs[128 * 72];
  const int tid = threadIdx.x;
  const int lane = tid & 63;
  const int wave = tid >> 6;
  const int wm = wave & 1, wn = wave >> 1;
  const int l15 = lane & 15, quad = lane >> 4;
  const int m0 = blockIdx.x * 128, n0 = blockIdx.y * 128;

  f32x4 acc[4][4] = {};

  for (int k0 = 0; k0 < kDim; k0 += 64) {
    __syncthreads();
#pragma unroll
    for (int i = 0; i < 4; ++i) {
      int c = tid + 256 * i;
      int row = c >> 3, kc = (c & 7) * 8;
      *(f16x8*)&As[row * 72 + kc] = *(const f16x8*)&A[(size_t)(m0 + row) * kDim + k0 + kc];
      *(f16x8*)&Bs[row * 72 + kc] = *(const f16x8*)&Bt[(size_t)(n0 + row) * kDim + k0 + kc];
    }
    __syncthreads();
#pragma unroll
    for (int kk = 0; kk < 2; ++kk) {
      f16x8 af[4], bf[4];
#pragma unroll
      for (int t = 0; t < 4; ++t) af[t] = *(const f16x8*)&As[(wm * 64 + t * 16 + l15) * 72 + kk * 32 + quad * 8];
#pragma unroll
      for (int t = 0; t < 4; ++t) bf[t] = *(const f16x8*)&Bs[(wn * 64 + t * 16 + l15) * 72 + kk * 32 + quad * 8];
#pragma unroll
      for (int i = 0; i < 4; ++i)
#pragma unroll
        for (int j = 0; j < 4; ++j)
          acc[i][j] = MFMA_16x16x32(af[i], bf[j], acc[i][j]);
    }
  }

  const int mbase = m0 + wm * 64 + quad * 4;
  const int nbase = n0 + wn * 64 + l15;
#pragma unroll
  for (int j = 0; j < 4; ++j) {
    int n = nbase + j * 16;
    float bv = bias[n];
#pragma unroll
    for (int i = 0; i < 4; ++i) {
      int mrow = mbase + i * 16;
#pragma unroll
      for (int r = 0; r < 4; ++r)
        out[(size_t)(mrow + r) * kDim + n] = acc[i][j][r] + bv;
    }
  }
}

extern "C" void kernel_launch(void* const* d_in, const int* in_sizes, int n_in,
                              void* d_out, int out_size, void* d_ws, size_t ws_size,
                              hipStream_t stream) {
  (void)in_sizes; (void)n_in; (void)out_size; (void)ws_size;
  const float* X    = (const float*)d_in[0];
  const float* mask = (const float*)d_in[1];
  const float* Wq   = (const float*)d_in[2];
  const float* bq   = (const float*)d_in[3];
  const float* Wk   = (const float*)d_in[4];
  const float* bk   = (const float*)d_in[5];
  const float* Wv   = (const float*)d_in[6];
  const float* bv   = (const float*)d_in[7];
  const float* Wo   = (const float*)d_in[8];
  const float* bo   = (const float*)d_in[9];
  float* out = (float*)d_out;

  char* ws = (char*)d_ws;
  _Float16* Xh   = (_Float16*)(ws);                        // 8 MB
  _Float16* Wqt  = (_Float16*)(ws + ((size_t)8  << 20));   // 2 MB each
  _Float16* Wkt  = (_Float16*)(ws + ((size_t)10 << 20));
  _Float16* Wvt  = (_Float16*)(ws + ((size_t)12 << 20));
  _Float16* Wot  = (_Float16*)(ws + ((size_t)14 << 20));
  _Float16* Qh   = (_Float16*)(ws + ((size_t)16 << 20));   // 8 MB each
  _Float16* Kh   = (_Float16*)(ws + ((size_t)24 << 20));
  _Float16* Vh   = (_Float16*)(ws + ((size_t)32 << 20));   // [B][H][D][S]
  _Float16* Ch   = (_Float16*)(ws + ((size_t)40 << 20));   // 8 MB
  float*    pen2 = (float*)   (ws + ((size_t)48 << 20));   // 16 KB

  cvt_f32_to_f16<<<dim3(kM * kDim / 8 / 256), dim3(256), 0, stream>>>(X, Xh, kM * kDim / 8);
  transpose_cvt_w<<<dim3(16, 16, 4), dim3(256), 0, stream>>>(Wq, Wk, Wv, Wo, Wqt, Wkt, Wvt, Wot);
  mask_penalty<<<dim3(16), dim3(256), 0, stream>>>(mask, pen2, kB * kS);
  gemm_qkv<<<dim3(32, 8, 3), dim3(256), 0, stream>>>(Xh, Wqt, Wkt, Wvt, bq, bk, bv, Qh, Kh, Vh);
  attn<<<dim3(16, 32), dim3(256), 0, stream>>>(Qh, Kh, Vh, pen2, Ch);
  gemm_out<<<dim3(32, 8), dim3(256), 0, stream>>>(Ch, Wot, bo, out);
}

// Round 8
// 215.092 us; speedup vs baseline: 1.3917x; 1.3917x over previous
//
#include <hip/hip_runtime.h>
#include <cstdint>
#include <cstddef>

typedef __attribute__((ext_vector_type(8))) _Float16 f16x8;
typedef __attribute__((ext_vector_type(4))) _Float16 f16x4;
typedef __attribute__((ext_vector_type(4))) float f32x4;

#define MFMA_16x16x32(a, b, c) __builtin_amdgcn_mfma_f32_16x16x32_f16((a), (b), (c), 0, 0, 0)

static constexpr int kB = 2, kS = 2048, kDim = 1024, kH = 16, kD = 64;
static constexpr int kM = kB * kS;  // 4096 rows total
// 1/sqrt(64) * log2(e), folded into Q at projection time
static constexpr float kQScale = 0.125f * 1.44269504088896340736f;

// ---------------- elementwise f32 -> f16 ----------------
__global__ void cvt_f32_to_f16(const float* __restrict__ in, _Float16* __restrict__ out, int n8) {
  int i = blockIdx.x * blockDim.x + threadIdx.x;
  if (i >= n8) return;
  const float4* p = (const float4*)in + (size_t)i * 2;
  float4 a = p[0], b = p[1];
  f16x8 h;
  h[0] = (_Float16)a.x; h[1] = (_Float16)a.y; h[2] = (_Float16)a.z; h[3] = (_Float16)a.w;
  h[4] = (_Float16)b.x; h[5] = (_Float16)b.y; h[6] = (_Float16)b.z; h[7] = (_Float16)b.w;
  ((f16x8*)out)[i] = h;
}

// ------------- W [K][N] f32  ->  Wt [N][K] f16 (4 matrices) -------------
__global__ void transpose_cvt_w(const float* __restrict__ w0, const float* __restrict__ w1,
                                const float* __restrict__ w2, const float* __restrict__ w3,
                                _Float16* __restrict__ o0, _Float16* __restrict__ o1,
                                _Float16* __restrict__ o2, _Float16* __restrict__ o3) {
  const float* w; _Float16* o;
  switch (blockIdx.z) {
    case 0: w = w0; o = o0; break;
    case 1: w = w1; o = o1; break;
    case 2: w = w2; o = o2; break;
    default: w = w3; o = o3; break;
  }
  __shared__ alignas(16) _Float16 tile[64][72];
  const int kt = blockIdx.x * 64;
  const int nt = blockIdx.y * 64;
  const int tr = threadIdx.x >> 4;
  const int tc = threadIdx.x & 15;
#pragma unroll
  for (int rr = 0; rr < 4; ++rr) {
    int r = rr * 16 + tr;
    float4 v = *(const float4*)&w[(size_t)(kt + r) * kDim + nt + tc * 4];
    f16x4 hv;
    hv[0] = (_Float16)v.x; hv[1] = (_Float16)v.y; hv[2] = (_Float16)v.z; hv[3] = (_Float16)v.w;
    *(f16x4*)&tile[r][tc * 4] = hv;
  }
  __syncthreads();
#pragma unroll
  for (int rr = 0; rr < 4; ++rr) {
    int nl = rr * 16 + tr;
    f16x4 hv;
    hv[0] = tile[tc * 4 + 0][nl];
    hv[1] = tile[tc * 4 + 1][nl];
    hv[2] = tile[tc * 4 + 2][nl];
    hv[3] = tile[tc * 4 + 3][nl];
    *(f16x4*)&o[(size_t)(nt + nl) * kDim + kt + tc * 4] = hv;
  }
}

// ------------- additive mask penalty, pre-scaled to log2 domain -------------
__global__ void mask_penalty(const float* __restrict__ mask, float* __restrict__ pen, int n) {
  int i = blockIdx.x * blockDim.x + threadIdx.x;
  if (i < n) pen[i] = -1.0e6f * (1.0f - mask[i]) * 1.44269504088896340736f;
}

// ------------- QKV projection GEMM (BK=64, double-buffered LDS, 1 barrier/iter) -------------
__global__ __launch_bounds__(256, 2) void gemm_qkv(
    const _Float16* __restrict__ A,
    const _Float16* __restrict__ wt0, const _Float16* __restrict__ wt1, const _Float16* __restrict__ wt2,
    const float* __restrict__ bias0, const float* __restrict__ bias1, const float* __restrict__ bias2,
    _Float16* __restrict__ oq, _Float16* __restrict__ ok, _Float16* __restrict__ ov) {
  const _Float16* Bt; const float* bias; _Float16* out;
  switch (blockIdx.z) {
    case 0: Bt = wt0; bias = bias0; out = oq; break;
    case 1: Bt = wt1; bias = bias1; out = ok; break;
    default: Bt = wt2; bias = bias2; out = ov; break;
  }
  __shared__ alignas(16) _Float16 As[2][128 * 72];
  __shared__ alignas(16) _Float16 Bs[2][128 * 72];
  const int tid = threadIdx.x;
  const int lane = tid & 63;
  const int wave = tid >> 6;
  const int wm = wave & 1, wn = wave >> 1;
  const int l15 = lane & 15, quad = lane >> 4;
  const int m0 = blockIdx.x * 128, n0 = blockIdx.y * 128;

  const int srow = tid >> 3;             // staging row (tid + 256*i -> row = srow + 32*i)
  const int skc = (tid & 7) * 8;         // staging k-offset

  f32x4 acc[4][4] = {};
  f16x8 ra[4], rb[4];

  // prologue: stage k0=0 into buffer 0
#pragma unroll
  for (int i = 0; i < 4; ++i) {
    int row = srow + 32 * i;
    ra[i] = *(const f16x8*)&A[(size_t)(m0 + row) * kDim + skc];
    rb[i] = *(const f16x8*)&Bt[(size_t)(n0 + row) * kDim + skc];
  }
#pragma unroll
  for (int i = 0; i < 4; ++i) {
    int row = srow + 32 * i;
    *(f16x8*)&As[0][row * 72 + skc] = ra[i];
    *(f16x8*)&Bs[0][row * 72 + skc] = rb[i];
  }

  for (int kt = 0; kt < 16; ++kt) {
    const int cur = kt & 1;
    // issue next tile's global loads early (latency hidden by MFMA below)
    if (kt + 1 < 16) {
      int k0 = (kt + 1) * 64;
#pragma unroll
      for (int i = 0; i < 4; ++i) {
        int row = srow + 32 * i;
        ra[i] = *(const f16x8*)&A[(size_t)(m0 + row) * kDim + k0 + skc];
        rb[i] = *(const f16x8*)&Bt[(size_t)(n0 + row) * kDim + k0 + skc];
      }
    }
    __syncthreads();  // writes to buffer `cur` (prev iter / prologue) complete
#pragma unroll
    for (int kk = 0; kk < 2; ++kk) {
      f16x8 af[4], bf[4];
#pragma unroll
      for (int t = 0; t < 4; ++t) af[t] = *(const f16x8*)&As[cur][(wm * 64 + t * 16 + l15) * 72 + kk * 32 + quad * 8];
#pragma unroll
      for (int t = 0; t < 4; ++t) bf[t] = *(const f16x8*)&Bs[cur][(wn * 64 + t * 16 + l15) * 72 + kk * 32 + quad * 8];
#pragma unroll
      for (int i = 0; i < 4; ++i)
#pragma unroll
        for (int j = 0; j < 4; ++j)
          acc[i][j] = MFMA_16x16x32(af[i], bf[j], acc[i][j]);
    }
    if (kt + 1 < 16) {
#pragma unroll
      for (int i = 0; i < 4; ++i) {
        int row = srow + 32 * i;
        *(f16x8*)&As[cur ^ 1][row * 72 + skc] = ra[i];
        *(f16x8*)&Bs[cur ^ 1][row * 72 + skc] = rb[i];
      }
    }
  }

  const int mbase = m0 + wm * 64 + quad * 4;
  const int nbase = n0 + wn * 64 + l15;
  if (blockIdx.z == 2) {
#pragma unroll
    for (int j = 0; j < 4; ++j) {
      int n = nbase + j * 16;
      float bv = bias[n];
      int h = n >> 6, d = n & 63;
#pragma unroll
      for (int i = 0; i < 4; ++i) {
        int m = mbase + i * 16;
        int b = m >> 11, s = m & (kS - 1);
        f16x4 hv;
#pragma unroll
        for (int r = 0; r < 4; ++r) hv[r] = (_Float16)(acc[i][j][r] + bv);
        *(f16x4*)&out[((size_t)((b * kH + h) * kD + d)) * kS + s] = hv;
      }
    }
  } else {
    const float osc = (blockIdx.z == 0) ? kQScale : 1.0f;
#pragma unroll
    for (int j = 0; j < 4; ++j) {
      int n = nbase + j * 16;
      float bv = bias[n];
      int h = n >> 6, d = n & 63;
#pragma unroll
      for (int i = 0; i < 4; ++i) {
        int mrow = mbase + i * 16;
#pragma unroll
        for (int r = 0; r < 4; ++r) {
          int m = mrow + r;
          int b = m >> 11, s = m & (kS - 1);
          out[(size_t)(((b * kH + h) * kS) + s) * kD + d] = (_Float16)((acc[i][j][r] + bv) * osc);
        }
      }
    }
  }
}

// ------------- flash attention, S^T formulation (R4 exact: 75.4 us known) -------------
__global__ __launch_bounds__(256, 2) void attn(
    const _Float16* __restrict__ Q, const _Float16* __restrict__ K,
    const _Float16* __restrict__ V, const float* __restrict__ pen2,
    _Float16* __restrict__ ctx) {
  const int bh = blockIdx.y;
  const int b = bh >> 4;
  const int q0 = blockIdx.x * 128;
  const int tid = threadIdx.x, lane = tid & 63, wave = tid >> 6;
  const int l15 = lane & 15, quad = lane >> 4;

  __shared__ alignas(16) _Float16 Ks[128 * 72];       // [key][d]
  __shared__ alignas(16) _Float16 Vs[64 * 136];       // [d][key]
  __shared__ alignas(16) _Float16 Pt[4][32 * 136];    // per-wave P^T [q][key]
  __shared__ alignas(16) float pens[128];

  const _Float16* Qh = Q + (size_t)bh * kS * kD;
  const _Float16* Kh = K + (size_t)bh * kS * kD;
  const _Float16* Vh = V + (size_t)bh * kS * kD;  // [d][s]

  f16x8 qf[2][2];
#pragma unroll
  for (int t = 0; t < 2; ++t) {
    int qrow = q0 + wave * 32 + t * 16 + l15;
#pragma unroll
    for (int kk = 0; kk < 2; ++kk)
      qf[t][kk] = *(const f16x8*)&Qh[(size_t)qrow * kD + kk * 32 + quad * 8];
  }

  f32x4 o_acc[2][4] = {};   // O^T: [t][d-tile], C-layout (row=d, col=q)
  float l_part[2] = {0.0f, 0.0f};

  for (int kb = 0; kb < kS; kb += 128) {
    __syncthreads();
#pragma unroll
    for (int i = 0; i < 4; ++i) {
      int c = tid + 256 * i;            // 1024 chunks: 128 rows x 8
      int row = c >> 3, dc = (c & 7) * 8;
      *(f16x8*)&Ks[row * 72 + dc] = *(const f16x8*)&Kh[(size_t)(kb + row) * kD + dc];
    }
#pragma unroll
    for (int i = 0; i < 4; ++i) {
      int c = tid + 256 * i;            // 1024 chunks: 64 rows x 16
      int row = c >> 4, sc8 = (c & 15) * 8;
      *(f16x8*)&Vs[row * 136 + sc8] = *(const f16x8*)&Vh[(size_t)row * kS + kb + sc8];
    }
    if (tid < 128) pens[tid] = pen2[b * kS + kb + tid];
    __syncthreads();

    // S^T = K Q^T : s[t][colt] covers keys colt*16.. x q-strip t (16 q)
    f32x4 s[2][8] = {};
#pragma unroll
    for (int kk = 0; kk < 2; ++kk)
#pragma unroll
      for (int colt = 0; colt < 8; ++colt) {
        f16x8 kf = *(const f16x8*)&Ks[(colt * 16 + l15) * 72 + kk * 32 + quad * 8];
        s[0][colt] = MFMA_16x16x32(kf, qf[0][kk], s[0][colt]);
        s[1][colt] = MFMA_16x16x32(kf, qf[1][kk], s[1][colt]);
      }

    // P = exp2(S^T + pen[key]); key = colt*16 + quad*4 + r lives in regs ->
    // pack 4 halves, single b64 LDS write per colt per t.
#pragma unroll
    for (int t = 0; t < 2; ++t) {
#pragma unroll
      for (int colt = 0; colt < 8; ++colt) {
        f32x4 pn = *(const f32x4*)&pens[colt * 16 + quad * 4];
        f16x4 ph;
#pragma unroll
        for (int r = 0; r < 4; ++r) {
          float pv = __builtin_exp2f(s[t][colt][r] + pn[r]);
          l_part[t] += pv;
          ph[r] = (_Float16)pv;
        }
        *(f16x4*)&Pt[wave][(t * 16 + l15) * 136 + colt * 16 + quad * 4] = ph;
      }
    }

    // O^T += V^T P^T : A=vf (shared across t), B=pf
#pragma unroll
    for (int ks = 0; ks < 4; ++ks) {
      f16x8 pf0 = *(const f16x8*)&Pt[wave][(l15) * 136 + ks * 32 + quad * 8];
      f16x8 pf1 = *(const f16x8*)&Pt[wave][(16 + l15) * 136 + ks * 32 + quad * 8];
#pragma unroll
      for (int c = 0; c < 4; ++c) {
        f16x8 vf = *(const f16x8*)&Vs[(c * 16 + l15) * 136 + ks * 32 + quad * 8];
        o_acc[0][c] = MFMA_16x16x32(vf, pf0, o_acc[0][c]);
        o_acc[1][c] = MFMA_16x16x32(vf, pf1, o_acc[1][c]);
      }
    }
  }

  // epilogue: l(q) = reduce over quads; O^T lane holds 4 consecutive d for q=l15
  const int h = bh & 15;
#pragma unroll
  for (int t = 0; t < 2; ++t) {
    float lsum = l_part[t];
    lsum += __shfl_xor(lsum, 16, 64);
    lsum += __shfl_xor(lsum, 32, 64);
    float inv = 1.0f / lsum;
    int q = q0 + wave * 32 + t * 16 + l15;
#pragma unroll
    for (int c = 0; c < 4; ++c) {
      f16x4 oh;
#pragma unroll
      for (int r = 0; r < 4; ++r) oh[r] = (_Float16)(o_acc[t][c][r] * inv);
      *(f16x4*)&ctx[((size_t)(b * kS + q)) * kDim + h * kD + c * 16 + quad * 4] = oh;
    }
  }
}

// ------------- output GEMM (BK=64, double-buffered LDS, 1 barrier/iter) -------------
__global__ __launch_bounds__(256, 2) void gemm_out(
    const _Float16* __restrict__ A, const _Float16* __restrict__ Bt,
    const float* __restrict__ bias, float* __restrict__ out) {
  __shared__ alignas(16) _Float16 As[2][128 * 72];
  __shared__ alignas(16) _Float16 Bs[2][128 * 72];
  const int tid = threadIdx.x;
  const int lane = tid & 63;
  const int wave = tid >> 6;
  const int wm = wave & 1, wn = wave >> 1;
  const int l15 = lane & 15, quad = lane >> 4;
  const int m0 = blockIdx.x * 128, n0 = blockIdx.y * 128;

  const int srow = tid >> 3;
  const int skc = (tid & 7) * 8;

  f32x4 acc[4][4] = {};
  f16x8 ra[4], rb[4];

#pragma unroll
  for (int i = 0; i < 4; ++i) {
    int row = srow + 32 * i;
    ra[i] = *(const f16x8*)&A[(size_t)(m0 + row) * kDim + skc];
    rb[i] = *(const f16x8*)&Bt[(size_t)(n0 + row) * kDim + skc];
  }
#pragma unroll
  for (int i = 0; i < 4; ++i) {
    int row = srow + 32 * i;
    *(f16x8*)&As[0][row * 72 + skc] = ra[i];
    *(f16x8*)&Bs[0][row * 72 + skc] = rb[i];
  }

  for (int kt = 0; kt < 16; ++kt) {
    const int cur = kt & 1;
    if (kt + 1 < 16) {
      int k0 = (kt + 1) * 64;
#pragma unroll
      for (int i = 0; i < 4; ++i) {
        int row = srow + 32 * i;
        ra[i] = *(const f16x8*)&A[(size_t)(m0 + row) * kDim + k0 + skc];
        rb[i] = *(const f16x8*)&Bt[(size_t)(n0 + row) * kDim + k0 + skc];
      }
    }
    __syncthreads();
#pragma unroll
    for (int kk = 0; kk < 2; ++kk) {
      f16x8 af[4], bf[4];
#pragma unroll
      for (int t = 0; t < 4; ++t) af[t] = *(const f16x8*)&As[cur][(wm * 64 + t * 16 + l15) * 72 + kk * 32 + quad * 8];
#pragma unroll
      for (int t = 0; t < 4; ++t) bf[t] = *(const f16x8*)&Bs[cur][(wn * 64 + t * 16 + l15) * 72 + kk * 32 + quad * 8];
#pragma unroll
      for (int i = 0; i < 4; ++i)
#pragma unroll
        for (int j = 0; j < 4; ++j)
          acc[i][j] = MFMA_16x16x32(af[i], bf[j], acc[i][j]);
    }
    if (kt + 1 < 16) {
#pragma unroll
      for (int i = 0; i < 4; ++i) {
        int row = srow + 32 * i;
        *(f16x8*)&As[cur ^ 1][row * 72 + skc] = ra[i];
        *(f16x8*)&Bs[cur ^ 1][row * 72 + skc] = rb[i];
      }
    }
  }

  const int mbase = m0 + wm * 64 + quad * 4;
  const int nbase = n0 + wn * 64 + l15;
#pragma unroll
  for (int j = 0; j < 4; ++j) {
    int n = nbase + j * 16;
    float bv = bias[n];
#pragma unroll
    for (int i = 0; i < 4; ++i) {
      int mrow = mbase + i * 16;
#pragma unroll
      for (int r = 0; r < 4; ++r)
        out[(size_t)(mrow + r) * kDim + n] = acc[i][j][r] + bv;
    }
  }
}

extern "C" void kernel_launch(void* const* d_in, const int* in_sizes, int n_in,
                              void* d_out, int out_size, void* d_ws, size_t ws_size,
                              hipStream_t stream) {
  (void)in_sizes; (void)n_in; (void)out_size; (void)ws_size;
  const float* X    = (const float*)d_in[0];
  const float* mask = (const float*)d_in[1];
  const float* Wq   = (const float*)d_in[2];
  const float* bq   = (const float*)d_in[3];
  const float* Wk   = (const float*)d_in[4];
  const float* bk   = (const float*)d_in[5];
  const float* Wv   = (const float*)d_in[6];
  const float* bv   = (const float*)d_in[7];
  const float* Wo   = (const float*)d_in[8];
  const float* bo   = (const float*)d_in[9];
  float* out = (float*)d_out;

  char* ws = (char*)d_ws;
  _Float16* Xh   = (_Float16*)(ws);                        // 8 MB
  _Float16* Wqt  = (_Float16*)(ws + ((size_t)8  << 20));   // 2 MB each
  _Float16* Wkt  = (_Float16*)(ws + ((size_t)10 << 20));
  _Float16* Wvt  = (_Float16*)(ws + ((size_t)12 << 20));
  _Float16* Wot  = (_Float16*)(ws + ((size_t)14 << 20));
  _Float16* Qh   = (_Float16*)(ws + ((size_t)16 << 20));   // 8 MB each
  _Float16* Kh   = (_Float16*)(ws + ((size_t)24 << 20));
  _Float16* Vh   = (_Float16*)(ws + ((size_t)32 << 20));   // [B][H][D][S]
  _Float16* Ch   = (_Float16*)(ws + ((size_t)40 << 20));   // 8 MB
  float*    pen2 = (float*)   (ws + ((size_t)48 << 20));   // 16 KB

  cvt_f32_to_f16<<<dim3(kM * kDim / 8 / 256), dim3(256), 0, stream>>>(X, Xh, kM * kDim / 8);
  transpose_cvt_w<<<dim3(16, 16, 4), dim3(256), 0, stream>>>(Wq, Wk, Wv, Wo, Wqt, Wkt, Wvt, Wot);
  mask_penalty<<<dim3(16), dim3(256), 0, stream>>>(mask, pen2, kB * kS);
  gemm_qkv<<<dim3(32, 8, 3), dim3(256), 0, stream>>>(Xh, Wqt, Wkt, Wvt, bq, bk, bv, Qh, Kh, Vh);
  attn<<<dim3(16, 32), dim3(256), 0, stream>>>(Qh, Kh, Vh, pen2, Ch);
  gemm_out<<<dim3(32, 8), dim3(256), 0, stream>>>(Ch, Wot, bo, out);
}